// Round 12
// baseline (15692.151 us; speedup 1.0000x reference)
//
#include <hip/hip_runtime.h>

// Problem constants (B,T,S,L,D_IN,OUT,W = 256,512,256,36,8,10,256)
#define Tt   512
#define Ll   36
#define DIN  8
#define OUTd 10

typedef __attribute__((ext_vector_type(8))) _Float16 half8;
typedef __attribute__((ext_vector_type(4))) float f32x4;
typedef unsigned short ushortT;

__device__ __forceinline__ unsigned short f2h(float f) {
    union { _Float16 h; unsigned short s; } u; u.h = (_Float16)f; return u.s;
}
__device__ __forceinline__ float h2f(unsigned short s) {
    union { unsigned short s; _Float16 h; } u; u.s = s; return (float)u.h;
}
__device__ __forceinline__ float sp_f(float x) {      // jax.nn.softplus
    return fmaxf(x, 0.f) + __logf(1.f + __expf(-fabsf(x)));
}
__device__ __forceinline__ float tanh_f(float x) {
    float e = __expf(2.f * x);
    return 1.f - 2.f / (e + 1.f);
}

// ---- agent-scope (sc1 / LLC-coherent) helpers: cross-XCD-safe ----
__device__ __forceinline__ unsigned long long ldg64(const void* p) {
    return __hip_atomic_load((const unsigned long long*)p, __ATOMIC_RELAXED, __HIP_MEMORY_SCOPE_AGENT);
}
__device__ __forceinline__ void stg64(void* p, unsigned long long v) {
    __hip_atomic_store((unsigned long long*)p, v, __ATOMIC_RELAXED, __HIP_MEMORY_SCOPE_AGENT);
}
__device__ __forceinline__ void sth(unsigned short* p, unsigned short v) {
    __hip_atomic_store(p, v, __ATOMIC_RELAXED, __HIP_MEMORY_SCOPE_AGENT);
}
union U64F2 { unsigned long long u; float f[2]; unsigned short s[4]; };

// ---- LDS layout (R12: buffers shared sequentially by the two chunk-halves) ----
struct GScr {
    short hh[16*264];                  // gathered h(t) for current half, fp16
    short z1[16*264];                  // stage-1 activations, fp16
    short z2[16*264];                  // stage-2 activations, fp16
    float lss[2][2][16*Ll];            // logsigs: [half][t-parity][576]
    float ml[16*296];                  // tanh(m) slice [16 rows x 288 n], f32 (pad 8)
};                                      // ~53.5 KB
struct IScr { float x0s[32][DIN]; float h1[32*257]; float h2[32*257]; };
union  Scr  { GScr g; IScr in; };

// ---- full-grid tree barrier (phase 0 only); touches slots[0 .. 512] inclusive ----
__device__ __forceinline__ void gbar(int* bar, int gen) {
    __syncthreads();
    if (threadIdx.x == 0) {
        const int g = blockIdx.x & 7;
        int old = __hip_atomic_fetch_add(bar + g * 32, 1, __ATOMIC_RELAXED, __HIP_MEMORY_SCOPE_AGENT);
        if (old == gen * 32 - 1) {
            int o2 = __hip_atomic_fetch_add(bar + 8 * 32, 1, __ATOMIC_RELAXED, __HIP_MEMORY_SCOPE_AGENT);
            if (o2 == gen * 8 - 1) {
#pragma unroll
                for (int gg = 0; gg < 8; ++gg)
                    __hip_atomic_store(bar + (9 + gg) * 32, gen, __ATOMIC_RELAXED, __HIP_MEMORY_SCOPE_AGENT);
            }
        }
        while (__hip_atomic_load(bar + (9 + g) * 32, __ATOMIC_RELAXED, __HIP_MEMORY_SCOPE_AGENT) < gen)
            __builtin_amdgcn_s_sleep(2);
    }
    __syncthreads();
}

// cast 8 consecutive k of W[n][k] (N x 256) into frag-contiguous transposed fp16:
// element (n,k) -> ((k>>5)*N + n)*32 + ((k>>3)&3)*8 + (k&7)
__device__ __forceinline__ void cast_w8n_h(const float* src, unsigned short* dh,
                                           long u, int N) {
    long n = u >> 5; int k8 = (int)(u & 31);
    const float* sp = src + n * 256 + k8 * 8;
    f32x4 f0 = *(const f32x4*)sp;
    f32x4 f1 = *(const f32x4*)(sp + 4);
    U64F2 H0, H1;
#pragma unroll
    for (int q = 0; q < 4; ++q) {
        H0.s[q] = f2h(f0[q]);
        H1.s[q] = f2h(f1[q]);
    }
    long d = ((long)(k8 >> 2) * N + n) * 32 + (k8 & 3) * 8;
    stg64(dh + d, H0.u);  stg64(dh + d + 4, H1.u);
}

// one MLP stage for 16 rows, 4-wave, fp16, register-resident B (R9):
// wave owns 4 n-tiles; WF[j][kt] holds the B-fragment. All indices static.
#define MLP_STAGE16R(Ah, WF, BIAS, Zh) do {                                                 \
    f32x4 acc_[4] = {zero4, zero4, zero4, zero4};                                            \
    _Pragma("unroll")                                                                        \
    for (int kt_ = 0; kt_ < 8; ++kt_) {                                                      \
      half8 ah_ = *(const half8*)(const void*)&(Ah)[l15 * 264 + kt_ * 32 + quad * 8];        \
      _Pragma("unroll")                                                                      \
      for (int j_ = 0; j_ < 4; ++j_)                                                         \
        acc_[j_] = __builtin_amdgcn_mfma_f32_16x16x32_f16(ah_, (WF)[j_][kt_], acc_[j_], 0, 0, 0); \
    }                                                                                        \
    _Pragma("unroll")                                                                        \
    for (int j_ = 0; j_ < 4; ++j_) {                                                         \
      int n_ = (4 * wv + j_) * 16 + l15;                                                     \
      float bs_ = (BIAS)[n_];                                                                \
      _Pragma("unroll")                                                                      \
      for (int r_ = 0; r_ < 4; ++r_) {                                                       \
        int row_ = quad * 4 + r_;                                                            \
        (Zh)[row_ * 264 + n_] = (short)f2h(sp_f(acc_[j_][r_] + bs_));                        \
      }                                                                                      \
    }                                                                                        \
  } while (0)

__global__ __launch_bounds__(256, 1) void rde_fused12(
    const float* __restrict__ x0, const float* __restrict__ logsigs,
    const float* __restrict__ iW1, const float* __restrict__ ib1,
    const float* __restrict__ iW2, const float* __restrict__ ib2,
    const float* __restrict__ iW3, const float* __restrict__ ib3,
    const float* __restrict__ vW1, const float* __restrict__ vb1,
    const float* __restrict__ vW2, const float* __restrict__ vb2,
    const float* __restrict__ vW3, const float* __restrict__ vb3,
    const float* __restrict__ roW, const float* __restrict__ rob,
    float* __restrict__ out,
    unsigned short* hA, unsigned short* hB, unsigned short* hC,
    unsigned short* w1t, unsigned short* w2t, unsigned short* w3t, int* slots) {
    __shared__ Scr S;
    __shared__ float hloc[256];   // [half][16 rows x 8 s], exact f32
    __shared__ float rtmp[44];    // readout partials (4 waves x 10)
    const int tid = threadIdx.x, blk = blockIdx.x;
    const int lane = tid & 63, wv = tid >> 6, quad = lane >> 4, l15 = lane & 15;
    // R12 partition: blk = p(b7b6) | c3(b5b4b3) | x(b2b1b0).
    // A-chunk = c3, B-chunk = c3+8 (16 rows each). slot s32 = (x<<2)|p in 0..31:
    // owns 8 s-cols + 288 W3 rows (144 KB). Same-XCD blocks (x fixed) share 4 W3
    // slices (576 KB, L2-resident); both halves reuse the SAME slice + W1/W2 regs.
    const int c3 = (blk >> 3) & 7;
    const int s32 = ((blk & 7) << 2) | (blk >> 6);
    const int s0g = s32 * 8;             // owned s-slice (8 cols)
    const int n0g = s32 * 288;           // owned W3 n-slice
    const int nnt = (wv < 2) ? 5 : 4;    // 18 n-tiles over 4 waves
    const f32x4 zero4 = {0.f, 0.f, 0.f, 0.f};

    // ===== phase 0: init MLP (blk<8), W1/W2 fp16 cast (8..15), W3 fp16 cast (16..255) =====
    if (blk < 8) {
        IScr& I = S.in;
        const int b0 = blk * 32;
        I.x0s[tid >> 3][tid & 7] = x0[(b0 + (tid >> 3)) * DIN + (tid & 7)];
        __syncthreads();
        const int j = tid;
        {
            float w[DIN];
#pragma unroll
            for (int k = 0; k < DIN; ++k) w[k] = iW1[j * DIN + k];
            float bias = ib1[j];
            for (int r = 0; r < 32; ++r) {
                float acc = bias;
#pragma unroll
                for (int k = 0; k < DIN; ++k) acc += I.x0s[r][k] * w[k];
                I.h1[r * 257 + j] = sp_f(acc);
            }
        }
        __syncthreads();
        {
            float bias = ib2[j];
            for (int rb = 0; rb < 4; ++rb) {
                float a8[8];
#pragma unroll
                for (int rr = 0; rr < 8; ++rr) a8[rr] = bias;
                for (int k = 0; k < 256; ++k) {
                    float wvv = iW2[j * 256 + k];
#pragma unroll
                    for (int rr = 0; rr < 8; ++rr) a8[rr] += I.h1[(rb * 8 + rr) * 257 + k] * wvv;
                }
#pragma unroll
                for (int rr = 0; rr < 8; ++rr) I.h2[(rb * 8 + rr) * 257 + j] = sp_f(a8[rr]);
            }
        }
        __syncthreads();
        {
            float bias = ib3[j];
            for (int rb = 0; rb < 4; ++rb) {
                float a8[8];
#pragma unroll
                for (int rr = 0; rr < 8; ++rr) a8[rr] = bias;
                for (int k = 0; k < 256; ++k) {
                    float wvv = iW3[j * 256 + k];
#pragma unroll
                    for (int rr = 0; rr < 8; ++rr) a8[rr] += I.h2[(rb * 8 + rr) * 257 + k] * wvv;
                }
#pragma unroll
                for (int rr = 0; rr < 8; ++rr)   // publish h0 as fp16 into buffer 0
                    sth(&hA[(b0 + rb * 8 + rr) * 256 + j], f2h(a8[rr]));
            }
        }
    } else if (blk < 16) {
        const int idx = blk - 8;
        const float* src = (idx < 4) ? vW1 : vW2;
        unsigned short* dh = (idx < 4) ? w1t : w2t;
        const int part = idx & 3;
        for (int u = part * 2048 + tid; u < (part + 1) * 2048; u += 256)
            cast_w8n_h(src, dh, u, 256);
    } else {
        for (long u = (long)(blk - 16) * 256 + tid; u < 9216L * 32; u += 240L * 256)
            cast_w8n_h(vW3, w3t, u, 9216);
    }
    gbar(slots, 1);

    // ===== load this wave's W1/W2 B-fragments into registers (t-invariant) =====
    half8 w1f[4][8], w2f[4][8];
#pragma unroll
    for (int j = 0; j < 4; ++j) {
        int n_ = (4 * wv + j) * 16 + l15;
#pragma unroll
        for (int kt = 0; kt < 8; ++kt) {
            long bo = ((long)kt * 256 + n_) * 32 + quad * 8;
            w1f[j][kt] = *(const half8*)(const void*)(w1t + bo);
            w2f[j][kt] = *(const half8*)(const void*)(w2t + bo);
        }
    }

    // init owned h sub-tiles, both halves (fp16 -> exact f32 accumulator)
    if (tid < 64) {
        int half = tid >> 5, u = tid & 31, r = u >> 1, part = u & 1;
        U64F2 a;
        a.u = ldg64(hA + ((c3 + 8 * half) * 16 + r) * 256 + s0g + part * 4);
#pragma unroll
        for (int q = 0; q < 4; ++q) hloc[half * 128 + r * 8 + part * 4 + q] = h2f(a.s[q]);
    }
    // prefetch logsigs t=0, both halves
    for (int i = tid; i < 2 * 16 * Ll; i += 256) {
        int half = i / 576, j = i - half * 576;
        int r = j / Ll, l = j - r * Ll;
        S.g.lss[half][0][j] = logsigs[((long)((c3 + 8 * half) * 16 + r) * Tt) * Ll + l];
    }
    __syncthreads();

    // 3-buffer rotation (R10 safety argument; A/B chunk rows are disjoint regions)
    const unsigned short* h_r = hA;
    unsigned short*       h_w = hB;
    unsigned short*       h_s = hC;

    // ================= main scan: 2 pipelined chunk-halves per round =================
    for (int t = 0; t < Tt; ++t) {
        GScr& G = S.g;
        for (int half = 0; half < 2; ++half) {
            const int b0cH = (c3 + 8 * half) * 16;
            int* fl = slots + 1024 + (c3 + 8 * half) * 32;

            // ---- wait: this chunk's 32 slot flags >= t (lanes 0..31 in parallel).
            // Peers set these before starting their other half -> ~1 compute-phase slack.
            for (;;) {
                int v = t;
                if (lane < 32)
                    v = __hip_atomic_load(fl + lane, __ATOMIC_RELAXED, __HIP_MEMORY_SCOPE_AGENT);
                if (__all(v >= t)) break;
                __builtin_amdgcn_s_sleep(1);
            }

            // ---- gather h(t) [16 rows x 256] fp16 into LDS ----
            for (int u = tid; u < 1024; u += 256) {
                int r = u >> 6, c4 = (u & 63) * 4;
                *(unsigned long long*)(void*)&G.hh[r * 264 + c4] =
                    ldg64(h_r + (b0cH + r) * 256 + c4);
            }
            __syncthreads();

            // ---- readout partials for row b0cH+s32 (slots 0..15 cover the 16 rows) ----
            if (s32 < 16 && lane < OUTd) {
                const int o = lane;
                float acc = 0.f;
                const short* ph = &G.hh[s32 * 264 + wv * 64];
                const float* wp = roW + o * 256 + wv * 64;
                for (int s = 0; s < 64; s += 8) {
                    half8 vh = *(const half8*)(const void*)(ph + s);
                    f32x4 w0 = *(const f32x4*)(wp + s);
                    f32x4 w1 = *(const f32x4*)(wp + s + 4);
#pragma unroll
                    for (int q = 0; q < 4; ++q) {
                        acc += (float)vh[q] * w0[q];
                        acc += (float)vh[q + 4] * w1[q];
                    }
                }
                rtmp[wv * 10 + o] = acc;
            }

            // ---- stage 1: z1 = sp(h W1^T) ----
            MLP_STAGE16R(G.hh, w1f, vb1, G.z1);
            __syncthreads();

            if (s32 < 16 && tid < OUTd)
                out[((long)(b0cH + s32) * 513 + t) * OUTd + tid] =
                    rob[tid] + rtmp[tid] + rtmp[10 + tid] + rtmp[20 + tid] + rtmp[30 + tid];

            // ---- stage 2: z2 = sp(z1 W2^T) ----
            MLP_STAGE16R(G.z1, w2f, vb2, G.z2);
            __syncthreads();

            // ---- W3 GEMM: m-pre = z2 @ W3slice^T (288 n, fp16 from L2) ----
            {
                f32x4 acc[5];
#pragma unroll
                for (int i = 0; i < 5; ++i) acc[i] = zero4;
                for (int kk = 0; kk < 8; ++kk) {
                    half8 ah = *(const half8*)(const void*)&G.z2[l15 * 264 + kk * 32 + quad * 8];
#pragma unroll
                    for (int i = 0; i < 5; ++i) {
                        if (i < nnt) {
                            int tile = wv + 4 * i;
                            long n = (long)n0g + tile * 16 + l15;
                            long bo = ((long)kk * 9216 + n) * 32 + quad * 8;
                            half8 bh = *(const half8*)(const void*)(w3t + bo);
                            acc[i] = __builtin_amdgcn_mfma_f32_16x16x32_f16(ah, bh, acc[i], 0, 0, 0);
                        }
                    }
                }
                // tanh epilogue -> ml [16][296]
#pragma unroll
                for (int i = 0; i < 5; ++i) {
                    if (i < nnt) {
                        int tile = wv + 4 * i;
                        int nloc = tile * 16 + l15;
                        float bias = vb3[n0g + nloc];
#pragma unroll
                        for (int r = 0; r < 4; ++r) {
                            int row = quad * 4 + r;
                            G.ml[row * 296 + nloc] = tanh_f(acc[i][r] + bias);
                        }
                    }
                }
            }
            __syncthreads();

            // ---- l-contraction: thread (r, sq) owns h[r][s0g+sq], sq in [0,8) ----
            if (tid < 128) {
                int r = tid >> 3, sq = tid & 7;
                const f32x4* mp = (const f32x4*)(const void*)&G.ml[r * 296 + sq * 36];
                const f32x4* lp = (const f32x4*)(const void*)&G.lss[half][t & 1][r * 36];
                float a = 0.f;
#pragma unroll
                for (int q = 0; q < 9; ++q) {
                    f32x4 m4 = mp[q], l4 = lp[q];
                    a += m4[0] * l4[0] + m4[1] * l4[1] + m4[2] * l4[2] + m4[3] * l4[3];
                }
                hloc[half * 128 + tid] += a;
            }
            __syncthreads();   // hloc complete before publish reads it

            // ---- publish owned [16 x 8] fp16 (wave 0), then RELEASE-store own flag ----
            if (tid < 32) {
                int r = tid >> 1, part = tid & 1;
                U64F2 H;
#pragma unroll
                for (int q = 0; q < 4; ++q)
                    H.s[q] = f2h(hloc[half * 128 + r * 8 + part * 4 + q]);
                stg64(h_w + (b0cH + r) * 256 + s0g + part * 4, H.u);
            }
            if (tid == 0)   // release orders wave 0's publish stores before the flag
                __hip_atomic_store(fl + s32, t + 1, __ATOMIC_RELEASE, __HIP_MEMORY_SCOPE_AGENT);

            // ---- overlap: prefetch this half's logsigs(t+1) ----
            if (t + 1 < Tt) {
                for (int i = tid; i < 16 * Ll; i += 256) {
                    int r = i / Ll, l = i - r * Ll;
                    G.lss[half][(t + 1) & 1][i] =
                        logsigs[((long)(b0cH + r) * Tt + (t + 1)) * Ll + l];
                }
            }
        }
        // rotate buffers once per round
        {
            const unsigned short* t0 = h_r;
            h_r = h_w; h_w = h_s; h_s = (unsigned short*)t0;
        }
    }

    // ---- final readout out[:, 512, :] ----
    for (int half = 0; half < 2; ++half) {
        int* fl = slots + 1024 + (c3 + 8 * half) * 32;
        for (;;) {
            int v = Tt;
            if (lane < 32)
                v = __hip_atomic_load(fl + lane, __ATOMIC_RELAXED, __HIP_MEMORY_SCOPE_AGENT);
            if (__all(v >= Tt)) break;
            __builtin_amdgcn_s_sleep(1);
        }
    }
    {
        float* fb = S.g.ml;   // reuse as f32 row buffer
        for (int half = 0; half < 2; ++half) {
            const int b0cH = (c3 + 8 * half) * 16;
            __syncthreads();
            if (s32 < 16 && tid < 64) {
                U64F2 a;
                a.u = ldg64(h_r + (long)(b0cH + s32) * 256 + tid * 4);
#pragma unroll
                for (int q = 0; q < 4; ++q) fb[tid * 4 + q] = h2f(a.s[q]);
            }
            __syncthreads();
            if (s32 < 16 && tid < OUTd) {
                float acc = rob[tid];
                const float* wp = roW + tid * 256;
                for (int s = 0; s < 256; s += 4) {
                    f32x4 hv = *(const f32x4*)(fb + s);
                    f32x4 w4 = *(const f32x4*)(wp + s);
                    acc += hv[0] * w4[0] + hv[1] * w4[1] + hv[2] * w4[2] + hv[3] * w4[3];
                }
                out[((long)(b0cH + s32) * 513 + Tt) * OUTd + tid] = acc;
            }
        }
    }
}

extern "C" void kernel_launch(void* const* d_in, const int* in_sizes, int n_in,
                              void* d_out, int out_size, void* d_ws, size_t ws_size,
                              hipStream_t stream) {
    const float* x0      = (const float*)d_in[0];
    const float* logsigs = (const float*)d_in[1];
    const float* iW1 = (const float*)d_in[2];
    const float* ib1 = (const float*)d_in[3];
    const float* iW2 = (const float*)d_in[4];
    const float* ib2 = (const float*)d_in[5];
    const float* iW3 = (const float*)d_in[6];
    const float* ib3 = (const float*)d_in[7];
    const float* vW1 = (const float*)d_in[8];
    const float* vb1 = (const float*)d_in[9];
    const float* vW2 = (const float*)d_in[10];
    const float* vb2 = (const float*)d_in[11];
    const float* vW3 = (const float*)d_in[12];
    const float* vb3 = (const float*)d_in[13];
    const float* roW = (const float*)d_in[14];
    const float* rob = (const float*)d_in[15];
    float* out = (float*)d_out;

    char* p = (char*)d_ws;
    unsigned short* hA   = (unsigned short*)p;                // 131072 B (fp16, buf 0)
    unsigned short* hB   = (unsigned short*)(p + 131072);     // 131072 B (buf 1)
    unsigned short* hC   = (unsigned short*)(p + 262144);     // 131072 B (buf 2)
    unsigned short* w1t  = (unsigned short*)(p + 393216);     // 131072 B (fp16)
    unsigned short* w2t  = (unsigned short*)(p + 524288);     // 131072 B (fp16)
    unsigned short* w3t  = (unsigned short*)(p + 655360);     // 4718592 B (fp16)
    int* slots           = (int*)(p + 10485760);              // gbar [0,512], flags [1024,1536)

    hipMemsetAsync(slots, 0, 8192, stream);
    rde_fused12<<<dim3(256), dim3(256), 0, stream>>>(
        x0, logsigs, iW1, ib1, iW2, ib2, iW3, ib3,
        vW1, vb1, vW2, vb2, vW3, vb3, roW, rob, out,
        hA, hB, hC, w1t, w2t, w3t, slots);
}

// Round 13
// 9912.264 us; speedup vs baseline: 1.5831x; 1.5831x over previous
//
#include <hip/hip_runtime.h>

// Problem constants (B,T,S,L,D_IN,OUT,W = 256,512,256,36,8,10,256)
#define Tt   512
#define Ll   36
#define DIN  8
#define OUTd 10

typedef __attribute__((ext_vector_type(8))) _Float16 half8;
typedef __attribute__((ext_vector_type(4))) float f32x4;

__device__ __forceinline__ unsigned short f2h(float f) {
    union { _Float16 h; unsigned short s; } u; u.h = (_Float16)f; return u.s;
}
__device__ __forceinline__ float h2f(unsigned short s) {
    union { unsigned short s; _Float16 h; } u; u.s = s; return (float)u.h;
}
__device__ __forceinline__ float sp_f(float x) {      // jax.nn.softplus
    return fmaxf(x, 0.f) + __logf(1.f + __expf(-fabsf(x)));
}
__device__ __forceinline__ float tanh_f(float x) {
    float e = __expf(2.f * x);
    return 1.f - 2.f / (e + 1.f);
}

// ---- agent-scope (sc1 / LLC-coherent) helpers: cross-XCD-safe ----
__device__ __forceinline__ unsigned long long ldg64(const void* p) {
    return __hip_atomic_load((const unsigned long long*)p, __ATOMIC_RELAXED, __HIP_MEMORY_SCOPE_AGENT);
}
__device__ __forceinline__ void stg64(void* p, unsigned long long v) {
    __hip_atomic_store((unsigned long long*)p, v, __ATOMIC_RELAXED, __HIP_MEMORY_SCOPE_AGENT);
}
__device__ __forceinline__ void sth(unsigned short* p, unsigned short v) {
    __hip_atomic_store(p, v, __ATOMIC_RELAXED, __HIP_MEMORY_SCOPE_AGENT);
}
union U64F2 { unsigned long long u; float f[2]; unsigned short s[4]; };

// ---- LDS layout (all activations single-plane fp16) ----
struct GScr {
    short hh[16*264];                  // gathered h(t), fp16
    short z1[16*264];                  // stage-1 activations, fp16
    short z2[16*264];                  // stage-2 activations, fp16
    float lss[2*576];                  // logsigs slice, double-buffered
    float ml[16*584];                  // tanh(m) slice [16 rows x 576 n], f32
};                                      // ~67 KB
struct IScr { float x0s[32][DIN]; float h1[32*257]; float h2[32*257]; };
union  Scr  { GScr g; IScr in; };

// ---- full-grid tree barrier (phase 0 only); touches slots[0 .. 512] inclusive ----
__device__ __forceinline__ void gbar(int* bar, int gen) {
    __syncthreads();
    if (threadIdx.x == 0) {
        const int g = blockIdx.x & 7;
        int old = __hip_atomic_fetch_add(bar + g * 32, 1, __ATOMIC_RELAXED, __HIP_MEMORY_SCOPE_AGENT);
        if (old == gen * 32 - 1) {
            int o2 = __hip_atomic_fetch_add(bar + 8 * 32, 1, __ATOMIC_RELAXED, __HIP_MEMORY_SCOPE_AGENT);
            if (o2 == gen * 8 - 1) {
#pragma unroll
                for (int gg = 0; gg < 8; ++gg)
                    __hip_atomic_store(bar + (9 + gg) * 32, gen, __ATOMIC_RELAXED, __HIP_MEMORY_SCOPE_AGENT);
            }
        }
        while (__hip_atomic_load(bar + (9 + g) * 32, __ATOMIC_RELAXED, __HIP_MEMORY_SCOPE_AGENT) < gen)
            __builtin_amdgcn_s_sleep(2);
    }
    __syncthreads();
}

// cast 8 consecutive k of W[n][k] (N x 256) into frag-contiguous transposed fp16:
// element (n,k) -> ((k>>5)*N + n)*32 + ((k>>3)&3)*8 + (k&7)
__device__ __forceinline__ void cast_w8n_h(const float* src, unsigned short* dh,
                                           long u, int N) {
    long n = u >> 5; int k8 = (int)(u & 31);
    const float* sp = src + n * 256 + k8 * 8;
    f32x4 f0 = *(const f32x4*)sp;
    f32x4 f1 = *(const f32x4*)(sp + 4);
    U64F2 H0, H1;
#pragma unroll
    for (int q = 0; q < 4; ++q) {
        H0.s[q] = f2h(f0[q]);
        H1.s[q] = f2h(f1[q]);
    }
    long d = ((long)(k8 >> 2) * N + n) * 32 + (k8 & 3) * 8;
    stg64(dh + d, H0.u);  stg64(dh + d + 4, H1.u);
}

// one MLP stage for 16 rows, 4-wave, fp16, register-resident B (R9):
// wave owns 4 n-tiles; WF[j][kt] holds the B-fragment. All indices static.
#define MLP_STAGE16R(Ah, WF, BIAS, Zh) do {                                                 \
    f32x4 acc_[4] = {zero4, zero4, zero4, zero4};                                            \
    _Pragma("unroll")                                                                        \
    for (int kt_ = 0; kt_ < 8; ++kt_) {                                                      \
      half8 ah_ = *(const half8*)(const void*)&(Ah)[l15 * 264 + kt_ * 32 + quad * 8];        \
      _Pragma("unroll")                                                                      \
      for (int j_ = 0; j_ < 4; ++j_)                                                         \
        acc_[j_] = __builtin_amdgcn_mfma_f32_16x16x32_f16(ah_, (WF)[j_][kt_], acc_[j_], 0, 0, 0); \
    }                                                                                        \
    _Pragma("unroll")                                                                        \
    for (int j_ = 0; j_ < 4; ++j_) {                                                         \
      int n_ = (4 * wv + j_) * 16 + l15;                                                     \
      float bs_ = (BIAS)[n_];                                                                \
      _Pragma("unroll")                                                                      \
      for (int r_ = 0; r_ < 4; ++r_) {                                                       \
        int row_ = quad * 4 + r_;                                                            \
        (Zh)[row_ * 264 + n_] = (short)f2h(sp_f(acc_[j_][r_] + bs_));                        \
      }                                                                                      \
    }                                                                                        \
  } while (0)

__global__ __launch_bounds__(256, 1) void rde_fused13(
    const float* __restrict__ x0, const float* __restrict__ logsigs,
    const float* __restrict__ iW1, const float* __restrict__ ib1,
    const float* __restrict__ iW2, const float* __restrict__ ib2,
    const float* __restrict__ iW3, const float* __restrict__ ib3,
    const float* __restrict__ vW1, const float* __restrict__ vb1,
    const float* __restrict__ vW2, const float* __restrict__ vb2,
    const float* __restrict__ vW3, const float* __restrict__ vb3,
    const float* __restrict__ roW, const float* __restrict__ rob,
    float* __restrict__ out,
    unsigned short* hA, unsigned short* hB, unsigned short* hC,
    unsigned short* w1t, unsigned short* w2t, unsigned short* w3t, int* slots) {
    __shared__ Scr S;
    __shared__ float hloc[256];   // owned h sub-tile [16 rows x 16 s], exact f32
    __shared__ float rtmp[44];    // readout partials (4 waves x 10)
    const int tid = threadIdx.x, blk = blockIdx.x;
    const int lane = tid & 63, wv = tid >> 6, quad = lane >> 4, l15 = lane & 15;
    // chunk = (blk>>3)&15, slot = ((blk&7)<<1)|(blk>>7): each XCD's 32 blocks share
    // only 2 W3 slices -> L2-resident (R6 lesson: 1 block/CU + synced chunks mandatory).
    const int chunk = (blk >> 3) & 15;
    const int sl = ((blk & 7) << 1) | (blk >> 7);
    const int b0c16 = chunk * 16;        // 16 batch rows owned by this chunk
    const int s0g = sl * 16;             // owned s-slice
    const int n0g = sl * 576;            // owned W3 n-slice
    // per-slot publish flags (monotone step counts); one writer each -> release STORE.
    int* flags = slots + 1024 + chunk * 16;
    const f32x4 zero4 = {0.f, 0.f, 0.f, 0.f};

    // ===== phase 0: init MLP (blk<8), W1/W2 fp16 cast (8..15), W3 fp16 cast (16..255) =====
    if (blk < 8) {
        IScr& I = S.in;
        const int b0 = blk * 32;
        I.x0s[tid >> 3][tid & 7] = x0[(b0 + (tid >> 3)) * DIN + (tid & 7)];
        __syncthreads();
        const int j = tid;
        {
            float w[DIN];
#pragma unroll
            for (int k = 0; k < DIN; ++k) w[k] = iW1[j * DIN + k];
            float bias = ib1[j];
            for (int r = 0; r < 32; ++r) {
                float acc = bias;
#pragma unroll
                for (int k = 0; k < DIN; ++k) acc += I.x0s[r][k] * w[k];
                I.h1[r * 257 + j] = sp_f(acc);
            }
        }
        __syncthreads();
        {
            float bias = ib2[j];
            for (int rb = 0; rb < 4; ++rb) {
                float a8[8];
#pragma unroll
                for (int rr = 0; rr < 8; ++rr) a8[rr] = bias;
                for (int k = 0; k < 256; ++k) {
                    float wvv = iW2[j * 256 + k];
#pragma unroll
                    for (int rr = 0; rr < 8; ++rr) a8[rr] += I.h1[(rb * 8 + rr) * 257 + k] * wvv;
                }
#pragma unroll
                for (int rr = 0; rr < 8; ++rr) I.h2[(rb * 8 + rr) * 257 + j] = sp_f(a8[rr]);
            }
        }
        __syncthreads();
        {
            float bias = ib3[j];
            for (int rb = 0; rb < 4; ++rb) {
                float a8[8];
#pragma unroll
                for (int rr = 0; rr < 8; ++rr) a8[rr] = bias;
                for (int k = 0; k < 256; ++k) {
                    float wvv = iW3[j * 256 + k];
#pragma unroll
                    for (int rr = 0; rr < 8; ++rr) a8[rr] += I.h2[(rb * 8 + rr) * 257 + k] * wvv;
                }
#pragma unroll
                for (int rr = 0; rr < 8; ++rr)   // publish h0 as fp16 into buffer 0
                    sth(&hA[(b0 + rb * 8 + rr) * 256 + j], f2h(a8[rr]));
            }
        }
    } else if (blk < 16) {
        const int idx = blk - 8;
        const float* src = (idx < 4) ? vW1 : vW2;
        unsigned short* dh = (idx < 4) ? w1t : w2t;
        const int part = idx & 3;
        for (int u = part * 2048 + tid; u < (part + 1) * 2048; u += 256)
            cast_w8n_h(src, dh, u, 256);
    } else {
        for (long u = (long)(blk - 16) * 256 + tid; u < 9216L * 32; u += 240L * 256)
            cast_w8n_h(vW3, w3t, u, 9216);
    }
    gbar(slots, 1);

    // ===== load this wave's W1/W2 B-fragments into registers (t-invariant) =====
    half8 w1f[4][8], w2f[4][8];
#pragma unroll
    for (int j = 0; j < 4; ++j) {
        int n_ = (4 * wv + j) * 16 + l15;
#pragma unroll
        for (int kt = 0; kt < 8; ++kt) {
            long bo = ((long)kt * 256 + n_) * 32 + quad * 8;
            w1f[j][kt] = *(const half8*)(const void*)(w1t + bo);
            w2f[j][kt] = *(const half8*)(const void*)(w2t + bo);
        }
    }

    // init owned h sub-tile (fp16 -> f32; owned trajectory accumulates in exact f32)
    if (tid < 64) {
        int r = tid >> 2, sq = tid & 3;
        U64F2 a;
        a.u = ldg64(hA + (b0c16 + r) * 256 + s0g + sq * 4);
#pragma unroll
        for (int q = 0; q < 4; ++q) hloc[r * 16 + sq * 4 + q] = h2f(a.s[q]);
    }
    // prefetch logsigs slice for t=0 into buffer 0
    for (int i = tid; i < 16 * Ll; i += 256) {
        int r = i / Ll, l = i - r * Ll;
        S.g.lss[i] = logsigs[((long)(b0c16 + r) * Tt) * Ll + l];
    }
    __syncthreads();

    // 3-buffer rotation (R10 safety argument: flags>=t gating bounds drift to <=1 step)
    const unsigned short* h_r = hA;   // read  h(t)
    unsigned short*       h_w = hB;   // write h(t+1)
    unsigned short*       h_s = hC;   // spare

    // W3 per-wave fragment addresses are t-invariant; precompute lane offsets
    // bfrag base offset for (kk, nt): ((kk*9216 + n0g + wv*144 + nt*16 + l15)*32 + quad*8)
    const long w3base = ((long)n0g + wv * 144 + l15) * 32 + quad * 8;

    // ================= main scan: flag-gated, W3 software-pipelined =================
    for (int t = 0; t < Tt; ++t) {
        GScr& G = S.g;

        // ---- wait: all 16 slot flags >= t (lanes 0..15 poll in parallel) ----
        for (;;) {
            int v = t;
            if (lane < 16)
                v = __hip_atomic_load(flags + lane, __ATOMIC_RELAXED, __HIP_MEMORY_SCOPE_AGENT);
            if (__all(v >= t)) break;
            __builtin_amdgcn_s_sleep(1);
        }

        // ---- gather h(t) [16 rows x 256] fp16 into LDS (coalesced u64 copies) ----
        for (int u = tid; u < 1024; u += 256) {
            int r = u >> 6, c4 = (u & 63) * 4;
            *(unsigned long long*)(void*)&G.hh[r * 264 + c4] = ldg64(h_r + (b0c16 + r) * 256 + c4);
        }
        __syncthreads();

        // ---- stage 1: z1 = sp(h W1^T)  (B register-resident) ----
        MLP_STAGE16R(G.hh, w1f, vb1, G.z1);
        __syncthreads();

        // ---- W3 pipeline: issue kk=0 fragment loads (independent of z2) ----
        half8 bfrag[2][9];
#pragma unroll
        for (int nt = 0; nt < 9; ++nt)
            bfrag[0][nt] = *(const half8*)(const void*)(w3t + w3base + (long)nt * 512);

        // ---- stage 2: z2 = sp(z1 W2^T)  (B register-resident; kk=0 loads in flight) ----
        MLP_STAGE16R(G.z1, w2f, vb2, G.z2);
        __syncthreads();

        // ---- W3 GEMM with rolling register prefetch (bit-identical accumulation) ----
        {
            f32x4 acc[9];
#pragma unroll
            for (int nt = 0; nt < 9; ++nt) acc[nt] = zero4;
#pragma unroll
            for (int kk = 0; kk < 8; ++kk) {
                const int cur = kk & 1, nxt = cur ^ 1;
                if (kk < 7) {
#pragma unroll
                    for (int nt = 0; nt < 9; ++nt)
                        bfrag[nxt][nt] = *(const half8*)(const void*)
                            (w3t + w3base + (long)(kk + 1) * 9216 * 32 + (long)nt * 512);
                }
                half8 ah = *(const half8*)(const void*)&G.z2[l15 * 264 + kk * 32 + quad * 8];
#pragma unroll
                for (int nt = 0; nt < 9; ++nt)
                    acc[nt] = __builtin_amdgcn_mfma_f32_16x16x32_f16(ah, bfrag[cur][nt], acc[nt], 0, 0, 0);
            }
            // tanh epilogue -> ml
#pragma unroll
            for (int nt = 0; nt < 9; ++nt) {
                int nloc = wv * 144 + nt * 16 + l15;
                float bias = vb3[n0g + nloc];
#pragma unroll
                for (int r = 0; r < 4; ++r) {
                    int row = quad * 4 + r;
                    G.ml[row * 584 + nloc] = tanh_f(acc[nt][r] + bias);
                }
            }
        }
        __syncthreads();

        // ---- l-contraction: thread (r, sL) owns h[r][s0g+sL]: hloc += dot36 ----
        {
            int r = tid >> 4, sL = tid & 15;
            const f32x4* mp = (const f32x4*)(const void*)&G.ml[r * 584 + sL * 36];
            const f32x4* lp = (const f32x4*)(const void*)&G.lss[(t & 1) * 576 + r * 36];
            float a = 0.f;
#pragma unroll
            for (int q = 0; q < 9; ++q) {
                f32x4 m4 = mp[q], l4 = lp[q];
                a += m4[0] * l4[0] + m4[1] * l4[1] + m4[2] * l4[2] + m4[3] * l4[3];
            }
            hloc[tid] += a;
        }
        __syncthreads();   // hloc complete (publish below reads all of it)

        // ---- publish owned h sub-tile fp16 (wave 0), then RELEASE-store own flag ----
        if (tid < 64) {
            int r = tid >> 2, sq = tid & 3;
            U64F2 H;
#pragma unroll
            for (int q = 0; q < 4; ++q) H.s[q] = f2h(hloc[r * 16 + sq * 4 + q]);
            stg64(h_w + (b0c16 + r) * 256 + s0g + sq * 4, H.u);
        }
        if (tid == 0)   // release orders wave 0's publish stores before the flag
            __hip_atomic_store(flags + sl, t + 1, __ATOMIC_RELEASE, __HIP_MEMORY_SCOPE_AGENT);

        // ==== wait-window work (off the critical chain) ====
        // readout of out[b0c16+sl, t, :] from G.hh (h(t) still resident in LDS)
        if (lane < OUTd) {
            const int o = lane;
            float acc = 0.f;
            const short* ph = &G.hh[sl * 264 + wv * 64];
            const float* wp = roW + o * 256 + wv * 64;
            for (int s = 0; s < 64; s += 8) {
                half8 vh = *(const half8*)(const void*)(ph + s);
                f32x4 w0 = *(const f32x4*)(wp + s);
                f32x4 w1 = *(const f32x4*)(wp + s + 4);
#pragma unroll
                for (int q = 0; q < 4; ++q) {
                    acc += (float)vh[q] * w0[q];
                    acc += (float)vh[q + 4] * w1[q];
                }
            }
            rtmp[wv * 10 + o] = acc;
        }
        // logsigs(t+1) prefetch (h-independent)
        if (t + 1 < Tt) {
            for (int i = tid; i < 16 * Ll; i += 256) {
                int r = i / Ll, l = i - r * Ll;
                G.lss[((t + 1) & 1) * 576 + i] =
                    logsigs[((long)(b0c16 + r) * Tt + (t + 1)) * Ll + l];
            }
        }
        __syncthreads();   // rtmp complete
        if (tid < OUTd)
            out[((long)(b0c16 + sl) * 513 + t) * OUTd + tid] =
                rob[tid] + rtmp[tid] + rtmp[10 + tid] + rtmp[20 + tid] + rtmp[30 + tid];

        // rotate buffers: next read = current write; next write = spare
        {
            const unsigned short* t0 = h_r;
            h_r = h_w; h_w = h_s; h_s = (unsigned short*)t0;
        }
    }

    // ---- final readout out[:, 512, :] from h(512) = h_r after 512 rotations ----
    {
        for (;;) {
            int v = Tt;
            if (lane < 16)
                v = __hip_atomic_load(flags + lane, __ATOMIC_RELAXED, __HIP_MEMORY_SCOPE_AGENT);
            if (__all(v >= Tt)) break;
            __builtin_amdgcn_s_sleep(1);
        }
        __syncthreads();
        float* fb = S.g.ml;   // reuse as f32 row buffer
        if (tid < 64) {
            U64F2 a;
            a.u = ldg64(h_r + (long)(b0c16 + sl) * 256 + tid * 4);
#pragma unroll
            for (int q = 0; q < 4; ++q) fb[tid * 4 + q] = h2f(a.s[q]);
        }
        __syncthreads();
        if (tid < OUTd) {
            float acc = rob[tid];
            const float* wp = roW + tid * 256;
            for (int s = 0; s < 256; s += 4) {
                f32x4 hv = *(const f32x4*)(fb + s);
                f32x4 w4 = *(const f32x4*)(wp + s);
                acc += hv[0] * w4[0] + hv[1] * w4[1] + hv[2] * w4[2] + hv[3] * w4[3];
            }
            out[((long)(b0c16 + sl) * 513 + Tt) * OUTd + tid] = acc;
        }
    }
}

extern "C" void kernel_launch(void* const* d_in, const int* in_sizes, int n_in,
                              void* d_out, int out_size, void* d_ws, size_t ws_size,
                              hipStream_t stream) {
    const float* x0      = (const float*)d_in[0];
    const float* logsigs = (const float*)d_in[1];
    const float* iW1 = (const float*)d_in[2];
    const float* ib1 = (const float*)d_in[3];
    const float* iW2 = (const float*)d_in[4];
    const float* ib2 = (const float*)d_in[5];
    const float* iW3 = (const float*)d_in[6];
    const float* ib3 = (const float*)d_in[7];
    const float* vW1 = (const float*)d_in[8];
    const float* vb1 = (const float*)d_in[9];
    const float* vW2 = (const float*)d_in[10];
    const float* vb2 = (const float*)d_in[11];
    const float* vW3 = (const float*)d_in[12];
    const float* vb3 = (const float*)d_in[13];
    const float* roW = (const float*)d_in[14];
    const float* rob = (const float*)d_in[15];
    float* out = (float*)d_out;

    char* p = (char*)d_ws;
    unsigned short* hA   = (unsigned short*)p;                // 131072 B (fp16, buf 0)
    unsigned short* hB   = (unsigned short*)(p + 131072);     // 131072 B (buf 1)
    unsigned short* hC   = (unsigned short*)(p + 262144);     // 131072 B (buf 2)
    unsigned short* w1t  = (unsigned short*)(p + 393216);     // 131072 B (fp16)
    unsigned short* w2t  = (unsigned short*)(p + 524288);     // 131072 B (fp16)
    unsigned short* w3t  = (unsigned short*)(p + 655360);     // 4718592 B (fp16)
    int* slots           = (int*)(p + 10485760);              // gbar [0,512], flags [1024,1280)

    hipMemsetAsync(slots, 0, 8192, stream);
    rde_fused13<<<dim3(256), dim3(256), 0, stream>>>(
        x0, logsigs, iW1, ib1, iW2, ib2, iW3, ib3,
        vW1, vb1, vW2, vb2, vW3, vb3, roW, rob, out,
        hA, hB, hC, w1t, w2t, w3t, slots);
}

// Round 14
// 8839.722 us; speedup vs baseline: 1.7752x; 1.1213x over previous
//
#include <hip/hip_runtime.h>

// Problem constants (B,T,S,L,D_IN,OUT,W = 256,512,256,36,8,10,256)
#define Tt   512
#define Ll   36
#define DIN  8
#define OUTd 10

typedef __attribute__((ext_vector_type(8))) _Float16 half8;
typedef __attribute__((ext_vector_type(4))) float f32x4;

__device__ __forceinline__ unsigned short f2h(float f) {
    union { _Float16 h; unsigned short s; } u; u.h = (_Float16)f; return u.s;
}
__device__ __forceinline__ float h2f(unsigned short s) {
    union { unsigned short s; _Float16 h; } u; u.s = s; return (float)u.h;
}
__device__ __forceinline__ float sp_f(float x) {      // jax.nn.softplus
    return fmaxf(x, 0.f) + __logf(1.f + __expf(-fabsf(x)));
}
__device__ __forceinline__ float tanh_f(float x) {
    float e = __expf(2.f * x);
    return 1.f - 2.f / (e + 1.f);
}

// ---- sc1 (LLC-coherent, cross-XCD) helpers: phase 0 / init / final only ----
__device__ __forceinline__ unsigned long long ldg64(const void* p) {
    return __hip_atomic_load((const unsigned long long*)p, __ATOMIC_RELAXED, __HIP_MEMORY_SCOPE_AGENT);
}
__device__ __forceinline__ void stg64(void* p, unsigned long long v) {
    __hip_atomic_store((unsigned long long*)p, v, __ATOMIC_RELAXED, __HIP_MEMORY_SCOPE_AGENT);
}
__device__ __forceinline__ void sth(unsigned short* p, unsigned short v) {
    __hip_atomic_store(p, v, __ATOMIC_RELAXED, __HIP_MEMORY_SCOPE_AGENT);
}
union U64F2 { unsigned long long u; float f[2]; unsigned short s[4]; };

// ---- LDS layout: 32-row chunk (R14). No overlay needed (LDS cap 160 KB) ----
struct GScr {
    short hh[32*264];                  // gathered h(t), fp16
    short z1[32*264];                  // stage-1 activations, fp16
    short z2[32*264];                  // stage-2 activations, fp16
    float lss[2*1152];                 // logsigs slice [parity][32*36]
    float ml[32*296];                  // tanh(m) slice [32 rows x 288 n], f32
};                                      // 97792 B
struct IScr { float x0s[32][DIN]; float h1[32*257]; float h2[32*257]; };
union  Scr  { GScr g; IScr in; };

// ---- full-grid tree barrier (phase 0 only); touches slots[0 .. 512] inclusive ----
__device__ __forceinline__ void gbar(int* bar, int gen) {
    __syncthreads();
    if (threadIdx.x == 0) {
        const int g = blockIdx.x & 7;
        int old = __hip_atomic_fetch_add(bar + g * 32, 1, __ATOMIC_RELAXED, __HIP_MEMORY_SCOPE_AGENT);
        if (old == gen * 32 - 1) {
            int o2 = __hip_atomic_fetch_add(bar + 8 * 32, 1, __ATOMIC_RELAXED, __HIP_MEMORY_SCOPE_AGENT);
            if (o2 == gen * 8 - 1) {
#pragma unroll
                for (int gg = 0; gg < 8; ++gg)
                    __hip_atomic_store(bar + (9 + gg) * 32, gen, __ATOMIC_RELAXED, __HIP_MEMORY_SCOPE_AGENT);
            }
        }
        while (__hip_atomic_load(bar + (9 + g) * 32, __ATOMIC_RELAXED, __HIP_MEMORY_SCOPE_AGENT) < gen)
            __builtin_amdgcn_s_sleep(2);
    }
    __syncthreads();
}

// cast 8 consecutive k of W[n][k] (N x 256) into frag-contiguous transposed fp16:
// element (n,k) -> ((k>>5)*N + n)*32 + ((k>>3)&3)*8 + (k&7)
__device__ __forceinline__ void cast_w8n_h(const float* src, unsigned short* dh,
                                           long u, int N) {
    long n = u >> 5; int k8 = (int)(u & 31);
    const float* sp = src + n * 256 + k8 * 8;
    f32x4 f0 = *(const f32x4*)sp;
    f32x4 f1 = *(const f32x4*)(sp + 4);
    U64F2 H0, H1;
#pragma unroll
    for (int q = 0; q < 4; ++q) {
        H0.s[q] = f2h(f0[q]);
        H1.s[q] = f2h(f1[q]);
    }
    long d = ((long)(k8 >> 2) * N + n) * 32 + (k8 & 3) * 8;
    stg64(dh + d, H0.u);  stg64(dh + d + 4, H1.u);
}

// one MLP stage for 32 rows (2 row-tiles), 4-wave, fp16, register-resident B:
// wave owns 4 n-tiles; WF[j][kt] = B-fragment. All indices static.
#define MLP_STAGE32R(Ah, WF, BIAS, Zh) do {                                                 \
    f32x4 acc_[2][4];                                                                        \
    _Pragma("unroll")                                                                        \
    for (int rt_ = 0; rt_ < 2; ++rt_)                                                        \
      { _Pragma("unroll")                                                                    \
        for (int j_ = 0; j_ < 4; ++j_) acc_[rt_][j_] = zero4; }                              \
    _Pragma("unroll")                                                                        \
    for (int kt_ = 0; kt_ < 8; ++kt_) {                                                      \
      half8 a0_ = *(const half8*)(const void*)&(Ah)[l15 * 264 + kt_ * 32 + quad * 8];        \
      half8 a1_ = *(const half8*)(const void*)&(Ah)[(16 + l15) * 264 + kt_ * 32 + quad * 8]; \
      _Pragma("unroll")                                                                      \
      for (int j_ = 0; j_ < 4; ++j_) {                                                       \
        acc_[0][j_] = __builtin_amdgcn_mfma_f32_16x16x32_f16(a0_, (WF)[j_][kt_], acc_[0][j_], 0, 0, 0); \
        acc_[1][j_] = __builtin_amdgcn_mfma_f32_16x16x32_f16(a1_, (WF)[j_][kt_], acc_[1][j_], 0, 0, 0); \
      }                                                                                      \
    }                                                                                        \
    _Pragma("unroll")                                                                        \
    for (int j_ = 0; j_ < 4; ++j_) {                                                         \
      int n_ = (4 * wv + j_) * 16 + l15;                                                     \
      float bs_ = (BIAS)[n_];                                                                \
      _Pragma("unroll")                                                                      \
      for (int rt_ = 0; rt_ < 2; ++rt_) {                                                    \
        _Pragma("unroll")                                                                    \
        for (int r_ = 0; r_ < 4; ++r_) {                                                     \
          int row_ = rt_ * 16 + quad * 4 + r_;                                               \
          (Zh)[row_ * 264 + n_] = (short)f2h(sp_f(acc_[rt_][j_][r_] + bs_));                 \
        }                                                                                    \
      }                                                                                      \
    }                                                                                        \
  } while (0)

__global__ __launch_bounds__(256, 1) void rde_fused14(
    const float* __restrict__ x0, const float* __restrict__ logsigs,
    const float* __restrict__ iW1, const float* __restrict__ ib1,
    const float* __restrict__ iW2, const float* __restrict__ ib2,
    const float* __restrict__ iW3, const float* __restrict__ ib3,
    const float* __restrict__ vW1, const float* __restrict__ vb1,
    const float* __restrict__ vW2, const float* __restrict__ vb2,
    const float* __restrict__ vW3, const float* __restrict__ vb3,
    const float* __restrict__ roW, const float* __restrict__ rob,
    float* __restrict__ out,
    unsigned short* hA, unsigned short* hB, unsigned short* hC,
    unsigned short* w1t, unsigned short* w2t, unsigned short* w3t, int* slots) {
    __shared__ Scr S;
    __shared__ float hloc[256];   // owned h sub-tile [32 rows x 8 s], exact f32
    __shared__ float rtmp[44];    // readout partials (4 waves x 10)
    const int tid = threadIdx.x, blk = blockIdx.x;
    const int lane = tid & 63, wv = tid >> 6, quad = lane >> 4, l15 = lane & 15;
    // R14 partition: chunk = blk&7 (== XCD under the empirically-verified blk%8 map);
    // all 32 blocks of a chunk share one XCD -> h exchange is L2-local (sc0).
    // slot = blk>>3 in 0..31: owns 8 s-cols + 288 W3 rows.
    const int chunk = blk & 7;
    const int slot = blk >> 3;
    const int b0c32 = chunk * 32;        // 32 batch rows owned by this chunk
    const int s0g = slot * 8;            // owned s-slice
    const int n0g = slot * 288;          // owned W3 n-slice
    const int nnt = (wv < 2) ? 5 : 4;    // 18 W3 n-tiles over 4 waves
    // per-slot publish flags, chunk-local (XCD-local): [1024, 1280) of slots
    int* flags = slots + 1024 + chunk * 32;
    const f32x4 zero4 = {0.f, 0.f, 0.f, 0.f};

    // ===== phase 0: init MLP (blk<8), W1/W2 fp16 cast (8..15), W3 fp16 cast (16..255) =====
    if (blk < 8) {
        IScr& I = S.in;
        const int b0 = blk * 32;
        I.x0s[tid >> 3][tid & 7] = x0[(b0 + (tid >> 3)) * DIN + (tid & 7)];
        __syncthreads();
        const int j = tid;
        {
            float w[DIN];
#pragma unroll
            for (int k = 0; k < DIN; ++k) w[k] = iW1[j * DIN + k];
            float bias = ib1[j];
            for (int r = 0; r < 32; ++r) {
                float acc = bias;
#pragma unroll
                for (int k = 0; k < DIN; ++k) acc += I.x0s[r][k] * w[k];
                I.h1[r * 257 + j] = sp_f(acc);
            }
        }
        __syncthreads();
        {
            float bias = ib2[j];
            for (int rb = 0; rb < 4; ++rb) {
                float a8[8];
#pragma unroll
                for (int rr = 0; rr < 8; ++rr) a8[rr] = bias;
                for (int k = 0; k < 256; ++k) {
                    float wvv = iW2[j * 256 + k];
#pragma unroll
                    for (int rr = 0; rr < 8; ++rr) a8[rr] += I.h1[(rb * 8 + rr) * 257 + k] * wvv;
                }
#pragma unroll
                for (int rr = 0; rr < 8; ++rr) I.h2[(rb * 8 + rr) * 257 + j] = sp_f(a8[rr]);
            }
        }
        __syncthreads();
        {
            float bias = ib3[j];
            for (int rb = 0; rb < 4; ++rb) {
                float a8[8];
#pragma unroll
                for (int rr = 0; rr < 8; ++rr) a8[rr] = bias;
                for (int k = 0; k < 256; ++k) {
                    float wvv = iW3[j * 256 + k];
#pragma unroll
                    for (int rr = 0; rr < 8; ++rr) a8[rr] += I.h2[(rb * 8 + rr) * 257 + k] * wvv;
                }
#pragma unroll
                for (int rr = 0; rr < 8; ++rr)   // publish h0 as fp16 into buffer 0 (sc1)
                    sth(&hA[(b0 + rb * 8 + rr) * 256 + j], f2h(a8[rr]));
            }
        }
    } else if (blk < 16) {
        const int idx = blk - 8;
        const float* src = (idx < 4) ? vW1 : vW2;
        unsigned short* dh = (idx < 4) ? w1t : w2t;
        const int part = idx & 3;
        for (int u = part * 2048 + tid; u < (part + 1) * 2048; u += 256)
            cast_w8n_h(src, dh, u, 256);
    } else {
        for (long u = (long)(blk - 16) * 256 + tid; u < 9216L * 32; u += 240L * 256)
            cast_w8n_h(vW3, w3t, u, 9216);
    }
    gbar(slots, 1);

    // ===== load this wave's W1/W2 B-fragments into registers (t-invariant) =====
    half8 w1f[4][8], w2f[4][8];
#pragma unroll
    for (int j = 0; j < 4; ++j) {
        int n_ = (4 * wv + j) * 16 + l15;
#pragma unroll
        for (int kt = 0; kt < 8; ++kt) {
            long bo = ((long)kt * 256 + n_) * 32 + quad * 8;
            w1f[j][kt] = *(const half8*)(const void*)(w1t + bo);
            w2f[j][kt] = *(const half8*)(const void*)(w2t + bo);
        }
    }

    // init owned h sub-tile [32 x 8] (sc1 read of h0 is safe; exact f32 accumulator)
    if (tid < 64) {
        int r = tid >> 1, part = tid & 1;
        U64F2 a;
        a.u = ldg64(hA + (b0c32 + r) * 256 + s0g + part * 4);
#pragma unroll
        for (int q = 0; q < 4; ++q) hloc[r * 8 + part * 4 + q] = h2f(a.s[q]);
    }
    // prefetch logsigs slice for t=0 into parity-0 buffer
    for (int i = tid; i < 32 * Ll; i += 256) {
        int r = i / Ll, l = i - r * Ll;
        S.g.lss[i] = logsigs[((long)(b0c32 + r) * Tt) * Ll + l];
    }
    __syncthreads();

    // 3-buffer rotation (flags>=t gating bounds drift to <=1 step; chunks independent)
    const unsigned short* h_r = hA;   // read  h(t)
    unsigned short*       h_w = hB;   // write h(t+1)
    unsigned short*       h_s = hC;   // spare

    // W3 fragment base (t-invariant): n = n0g + (wv+4i)*16 + l15, byte (n*32 + quad*8)
    const long w3base = ((long)n0g + wv * 16 + l15) * 32 + quad * 8;

    // ================= main scan: XCD-local sc0 exchange =================
    for (int t = 0; t < Tt; ++t) {
        GScr& G = S.g;

        // ---- wait: chunk's 32 slot flags >= t (lanes 0..31 poll in parallel, sc0/L2) ----
        for (;;) {
            int v = t;
            if (lane < 32) {
                const int* fp = flags + lane;
                asm volatile("global_load_dword %0, %1, off sc0\n\ts_waitcnt vmcnt(0)"
                             : "=v"(v) : "v"(fp) : "memory");
            }
            if (__all(v >= t)) break;
            __builtin_amdgcn_s_sleep(1);
        }

        // ---- gather h(t) [32 rows x 256] fp16 via sc0 (8 loads, one waitcnt) ----
        {
            const int r0 = tid >> 6, c4 = (tid & 63) * 4;
            const unsigned short* gp = h_r + (b0c32 + r0) * 256 + c4;
            unsigned long long v0, v1, v2, v3, v4, v5, v6, v7;
            asm volatile(
                "global_load_dwordx2 %0, %8, off sc0\n\t"
                "global_load_dwordx2 %1, %9, off sc0\n\t"
                "global_load_dwordx2 %2, %10, off sc0\n\t"
                "global_load_dwordx2 %3, %11, off sc0\n\t"
                "global_load_dwordx2 %4, %12, off sc0\n\t"
                "global_load_dwordx2 %5, %13, off sc0\n\t"
                "global_load_dwordx2 %6, %14, off sc0\n\t"
                "global_load_dwordx2 %7, %15, off sc0\n\t"
                "s_waitcnt vmcnt(0)"
                : "=&v"(v0), "=&v"(v1), "=&v"(v2), "=&v"(v3),
                  "=&v"(v4), "=&v"(v5), "=&v"(v6), "=&v"(v7)
                : "v"(gp), "v"(gp + 1024), "v"(gp + 2048), "v"(gp + 3072),
                  "v"(gp + 4096), "v"(gp + 5120), "v"(gp + 6144), "v"(gp + 7168)
                : "memory");
            *(unsigned long long*)(void*)&G.hh[(r0     ) * 264 + c4] = v0;
            *(unsigned long long*)(void*)&G.hh[(r0 +  4) * 264 + c4] = v1;
            *(unsigned long long*)(void*)&G.hh[(r0 +  8) * 264 + c4] = v2;
            *(unsigned long long*)(void*)&G.hh[(r0 + 12) * 264 + c4] = v3;
            *(unsigned long long*)(void*)&G.hh[(r0 + 16) * 264 + c4] = v4;
            *(unsigned long long*)(void*)&G.hh[(r0 + 20) * 264 + c4] = v5;
            *(unsigned long long*)(void*)&G.hh[(r0 + 24) * 264 + c4] = v6;
            *(unsigned long long*)(void*)&G.hh[(r0 + 28) * 264 + c4] = v7;
        }
        __syncthreads();

        // ---- stage 1: z1 = sp(h W1^T)  (B register-resident) ----
        MLP_STAGE32R(G.hh, w1f, vb1, G.z1);
        __syncthreads();

        // ---- W3 pipeline: pre-issue kk=0 fragment loads (independent of z2) ----
        half8 bfrag[2][5];
#pragma unroll
        for (int i = 0; i < 5; ++i)
            if (i < nnt)
                bfrag[0][i] = *(const half8*)(const void*)(w3t + w3base + (long)i * 2048);

        // ---- stage 2: z2 = sp(z1 W2^T)  (kk=0 loads in flight) ----
        MLP_STAGE32R(G.z1, w2f, vb2, G.z2);
        __syncthreads();

        // ---- W3 GEMM (2 row-tiles) with rolling register prefetch ----
        {
            f32x4 acc[2][5];
#pragma unroll
            for (int rt = 0; rt < 2; ++rt)
#pragma unroll
                for (int i = 0; i < 5; ++i) acc[rt][i] = zero4;
#pragma unroll
            for (int kk = 0; kk < 8; ++kk) {
                const int cur = kk & 1, nxt = cur ^ 1;
                if (kk < 7) {
#pragma unroll
                    for (int i = 0; i < 5; ++i)
                        if (i < nnt)
                            bfrag[nxt][i] = *(const half8*)(const void*)
                                (w3t + w3base + (long)(kk + 1) * 294912 + (long)i * 2048);
                }
                half8 ah0 = *(const half8*)(const void*)&G.z2[l15 * 264 + kk * 32 + quad * 8];
                half8 ah1 = *(const half8*)(const void*)&G.z2[(16 + l15) * 264 + kk * 32 + quad * 8];
#pragma unroll
                for (int i = 0; i < 5; ++i)
                    if (i < nnt) {
                        acc[0][i] = __builtin_amdgcn_mfma_f32_16x16x32_f16(ah0, bfrag[cur][i], acc[0][i], 0, 0, 0);
                        acc[1][i] = __builtin_amdgcn_mfma_f32_16x16x32_f16(ah1, bfrag[cur][i], acc[1][i], 0, 0, 0);
                    }
            }
            // tanh epilogue -> ml
#pragma unroll
            for (int i = 0; i < 5; ++i)
                if (i < nnt) {
                    int nloc = (wv + 4 * i) * 16 + l15;
                    float bias = vb3[n0g + nloc];
#pragma unroll
                    for (int rt = 0; rt < 2; ++rt)
#pragma unroll
                        for (int r = 0; r < 4; ++r) {
                            int row = rt * 16 + quad * 4 + r;
                            G.ml[row * 296 + nloc] = tanh_f(acc[rt][i][r] + bias);
                        }
                }
        }
        __syncthreads();

        // ---- l-contraction: thread (row, sq) owns h[row][s0g+sq]: hloc += dot36 ----
        {
            int row = tid >> 3, sq = tid & 7;
            const f32x4* mp = (const f32x4*)(const void*)&G.ml[row * 296 + sq * 36];
            const f32x4* lp = (const f32x4*)(const void*)&G.lss[(t & 1) * 1152 + row * 36];
            float a = 0.f;
#pragma unroll
            for (int q = 0; q < 9; ++q) {
                f32x4 m4 = mp[q], l4 = lp[q];
                a += m4[0] * l4[0] + m4[1] * l4[1] + m4[2] * l4[2] + m4[3] * l4[3];
            }
            hloc[tid] += a;
        }
        __syncthreads();   // hloc complete

        // ---- publish owned [32 x 8] fp16 via sc0 (wave 0), fence, sc0 flag store ----
        if (tid < 64) {
            int r = tid >> 1, part = tid & 1;
            U64F2 H;
#pragma unroll
            for (int q = 0; q < 4; ++q) H.s[q] = f2h(hloc[r * 8 + part * 4 + q]);
            unsigned short* pp = h_w + (b0c32 + r) * 256 + s0g + part * 4;
            asm volatile("global_store_dwordx2 %0, %1, off sc0" :: "v"(pp), "v"(H.u) : "memory");
            asm volatile("s_waitcnt vmcnt(0)" ::: "memory");
            if (tid == 0) {
                int* fp = flags + slot;
                int fv = t + 1;
                asm volatile("global_store_dword %0, %1, off sc0" :: "v"(fp), "v"(fv) : "memory");
            }
        }

        // ==== wait-window work (off the critical chain) ====
        // readout of out[b0c32+slot, t, :] from G.hh (h(t) resident in LDS)
        if (lane < OUTd) {
            const int o = lane;
            float acc = 0.f;
            const short* ph = &G.hh[slot * 264 + wv * 64];
            const float* wp = roW + o * 256 + wv * 64;
            for (int s = 0; s < 64; s += 8) {
                half8 vh = *(const half8*)(const void*)(ph + s);
                f32x4 w0 = *(const f32x4*)(wp + s);
                f32x4 w1 = *(const f32x4*)(wp + s + 4);
#pragma unroll
                for (int q = 0; q < 4; ++q) {
                    acc += (float)vh[q] * w0[q];
                    acc += (float)vh[q + 4] * w1[q];
                }
            }
            rtmp[wv * 10 + o] = acc;
        }
        // logsigs(t+1) prefetch (h-independent)
        if (t + 1 < Tt) {
            for (int i = tid; i < 32 * Ll; i += 256) {
                int r = i / Ll, l = i - r * Ll;
                G.lss[((t + 1) & 1) * 1152 + i] =
                    logsigs[((long)(b0c32 + r) * Tt + (t + 1)) * Ll + l];
            }
        }
        __syncthreads();   // rtmp complete
        if (tid < OUTd)
            out[((long)(b0c32 + slot) * 513 + t) * OUTd + tid] =
                rob[tid] + rtmp[tid] + rtmp[10 + tid] + rtmp[20 + tid] + rtmp[30 + tid];

        // rotate buffers
        {
            const unsigned short* t0 = h_r;
            h_r = h_w; h_w = h_s; h_s = (unsigned short*)t0;
        }
    }

    // ---- final readout out[:, 512, :] from h(512) = h_r ----
    {
        for (;;) {
            int v = Tt;
            if (lane < 32) {
                const int* fp = flags + lane;
                asm volatile("global_load_dword %0, %1, off sc0\n\ts_waitcnt vmcnt(0)"
                             : "=v"(v) : "v"(fp) : "memory");
            }
            if (__all(v >= Tt)) break;
            __builtin_amdgcn_s_sleep(1);
        }
        __syncthreads();
        float* fb = S.g.ml;   // reuse as f32 row buffer
        if (tid < 64) {
            int c4 = tid * 4;
            const unsigned short* pp = h_r + (long)(b0c32 + slot) * 256 + c4;
            unsigned long long a;
            asm volatile("global_load_dwordx2 %0, %1, off sc0\n\ts_waitcnt vmcnt(0)"
                         : "=v"(a) : "v"(pp) : "memory");
            U64F2 u; u.u = a;
#pragma unroll
            for (int q = 0; q < 4; ++q) fb[c4 + q] = h2f(u.s[q]);
        }
        __syncthreads();
        if (tid < OUTd) {
            float acc = rob[tid];
            const float* wp = roW + tid * 256;
            for (int s = 0; s < 256; s += 4) {
                f32x4 hv = *(const f32x4*)(fb + s);
                f32x4 w4 = *(const f32x4*)(wp + s);
                acc += hv[0] * w4[0] + hv[1] * w4[1] + hv[2] * w4[2] + hv[3] * w4[3];
            }
            out[((long)(b0c32 + slot) * 513 + Tt) * OUTd + tid] = acc;
        }
    }
}

extern "C" void kernel_launch(void* const* d_in, const int* in_sizes, int n_in,
                              void* d_out, int out_size, void* d_ws, size_t ws_size,
                              hipStream_t stream) {
    const float* x0      = (const float*)d_in[0];
    const float* logsigs = (const float*)d_in[1];
    const float* iW1 = (const float*)d_in[2];
    const float* ib1 = (const float*)d_in[3];
    const float* iW2 = (const float*)d_in[4];
    const float* ib2 = (const float*)d_in[5];
    const float* iW3 = (const float*)d_in[6];
    const float* ib3 = (const float*)d_in[7];
    const float* vW1 = (const float*)d_in[8];
    const float* vb1 = (const float*)d_in[9];
    const float* vW2 = (const float*)d_in[10];
    const float* vb2 = (const float*)d_in[11];
    const float* vW3 = (const float*)d_in[12];
    const float* vb3 = (const float*)d_in[13];
    const float* roW = (const float*)d_in[14];
    const float* rob = (const float*)d_in[15];
    float* out = (float*)d_out;

    char* p = (char*)d_ws;
    unsigned short* hA   = (unsigned short*)p;                // 131072 B (fp16, buf 0)
    unsigned short* hB   = (unsigned short*)(p + 131072);     // 131072 B (buf 1)
    unsigned short* hC   = (unsigned short*)(p + 262144);     // 131072 B (buf 2)
    unsigned short* w1t  = (unsigned short*)(p + 393216);     // 131072 B (fp16)
    unsigned short* w2t  = (unsigned short*)(p + 524288);     // 131072 B (fp16)
    unsigned short* w3t  = (unsigned short*)(p + 655360);     // 4718592 B (fp16)
    int* slots           = (int*)(p + 10485760);              // gbar [0,512], flags [1024,1280)

    hipMemsetAsync(slots, 0, 8192, stream);
    rde_fused14<<<dim3(256), dim3(256), 0, stream>>>(
        x0, logsigs, iW1, ib1, iW2, ib2, iW3, ib3,
        vW1, vb1, vW2, vb2, vW3, vb3, roW, rob, out,
        hA, hB, hC, w1t, w2t, w3t, slots);
}

// Round 15
// 6743.709 us; speedup vs baseline: 2.3269x; 1.3108x over previous
//
#include <hip/hip_runtime.h>

// Problem constants (B,T,S,L,D_IN,OUT,W = 256,512,256,36,8,10,256)
#define Tt   512
#define Ll   36
#define DIN  8
#define OUTd 10

typedef __attribute__((ext_vector_type(8))) _Float16 half8;
typedef __attribute__((ext_vector_type(4))) float f32x4;

__device__ __forceinline__ unsigned short f2h(float f) {
    union { _Float16 h; unsigned short s; } u; u.h = (_Float16)f; return u.s;
}
__device__ __forceinline__ float h2f(unsigned short s) {
    union { unsigned short s; _Float16 h; } u; u.s = s; return (float)u.h;
}
__device__ __forceinline__ float sp_f(float x) {      // jax.nn.softplus
    return fmaxf(x, 0.f) + __logf(1.f + __expf(-fabsf(x)));
}
__device__ __forceinline__ float tanh_f(float x) {
    float e = __expf(2.f * x);
    return 1.f - 2.f / (e + 1.f);
}

// ---- sc1 (LLC-coherent, cross-XCD) helpers: phase 0 / init only ----
__device__ __forceinline__ unsigned long long ldg64(const void* p) {
    return __hip_atomic_load((const unsigned long long*)p, __ATOMIC_RELAXED, __HIP_MEMORY_SCOPE_AGENT);
}
__device__ __forceinline__ void stg64(void* p, unsigned long long v) {
    __hip_atomic_store((unsigned long long*)p, v, __ATOMIC_RELAXED, __HIP_MEMORY_SCOPE_AGENT);
}
__device__ __forceinline__ void sth(unsigned short* p, unsigned short v) {
    __hip_atomic_store(p, v, __ATOMIC_RELAXED, __HIP_MEMORY_SCOPE_AGENT);
}
union U64F2 { unsigned long long u; float f[2]; unsigned short s[4]; };

// ---- LDS layout: 32-row chunk ----
struct GScr {
    short hh[32*264];                  // gathered h(t), fp16
    short z1[32*264];                  // stage-1 activations, fp16
    short z2[32*264];                  // stage-2 activations, fp16
    float lss[2*1152];                 // logsigs slice [parity][32*36]
    float ml[32*296];                  // tanh(m) slice [32 rows x 288 n], f32
};                                      // 97792 B
struct IScr { float x0s[32][DIN]; float h1[32*257]; float h2[32*257]; };
union  Scr  { GScr g; IScr in; };

// ---- full-grid tree barrier (phase 0 only); touches slots[0 .. 512] inclusive ----
__device__ __forceinline__ void gbar(int* bar, int gen) {
    __syncthreads();
    if (threadIdx.x == 0) {
        const int g = blockIdx.x & 7;
        int old = __hip_atomic_fetch_add(bar + g * 32, 1, __ATOMIC_RELAXED, __HIP_MEMORY_SCOPE_AGENT);
        if (old == gen * 32 - 1) {
            int o2 = __hip_atomic_fetch_add(bar + 8 * 32, 1, __ATOMIC_RELAXED, __HIP_MEMORY_SCOPE_AGENT);
            if (o2 == gen * 8 - 1) {
#pragma unroll
                for (int gg = 0; gg < 8; ++gg)
                    __hip_atomic_store(bar + (9 + gg) * 32, gen, __ATOMIC_RELAXED, __HIP_MEMORY_SCOPE_AGENT);
            }
        }
        while (__hip_atomic_load(bar + (9 + g) * 32, __ATOMIC_RELAXED, __HIP_MEMORY_SCOPE_AGENT) < gen)
            __builtin_amdgcn_s_sleep(2);
    }
    __syncthreads();
}

// cast 8 consecutive k of W[n][k] (N x 256) into frag-contiguous transposed fp16:
// element (n,k) -> ((k>>5)*N + n)*32 + ((k>>3)&3)*8 + (k&7)
__device__ __forceinline__ void cast_w8n_h(const float* src, unsigned short* dh,
                                           long u, int N) {
    long n = u >> 5; int k8 = (int)(u & 31);
    const float* sp = src + n * 256 + k8 * 8;
    f32x4 f0 = *(const f32x4*)sp;
    f32x4 f1 = *(const f32x4*)(sp + 4);
    U64F2 H0, H1;
#pragma unroll
    for (int q = 0; q < 4; ++q) {
        H0.s[q] = f2h(f0[q]);
        H1.s[q] = f2h(f1[q]);
    }
    long d = ((long)(k8 >> 2) * N + n) * 32 + (k8 & 3) * 8;
    stg64(dh + d, H0.u);  stg64(dh + d + 4, H1.u);
}

// one MLP stage for 32 rows (2 row-tiles), 4-wave, fp16, register-resident B:
#define MLP_STAGE32R(Ah, WF, BIAS, Zh) do {                                                 \
    f32x4 acc_[2][4];                                                                        \
    _Pragma("unroll")                                                                        \
    for (int rt_ = 0; rt_ < 2; ++rt_)                                                        \
      { _Pragma("unroll")                                                                    \
        for (int j_ = 0; j_ < 4; ++j_) acc_[rt_][j_] = zero4; }                              \
    _Pragma("unroll")                                                                        \
    for (int kt_ = 0; kt_ < 8; ++kt_) {                                                      \
      half8 a0_ = *(const half8*)(const void*)&(Ah)[l15 * 264 + kt_ * 32 + quad * 8];        \
      half8 a1_ = *(const half8*)(const void*)&(Ah)[(16 + l15) * 264 + kt_ * 32 + quad * 8]; \
      _Pragma("unroll")                                                                      \
      for (int j_ = 0; j_ < 4; ++j_) {                                                       \
        acc_[0][j_] = __builtin_amdgcn_mfma_f32_16x16x32_f16(a0_, (WF)[j_][kt_], acc_[0][j_], 0, 0, 0); \
        acc_[1][j_] = __builtin_amdgcn_mfma_f32_16x16x32_f16(a1_, (WF)[j_][kt_], acc_[1][j_], 0, 0, 0); \
      }                                                                                      \
    }                                                                                        \
    _Pragma("unroll")                                                                        \
    for (int j_ = 0; j_ < 4; ++j_) {                                                         \
      int n_ = (4 * wv + j_) * 16 + l15;                                                     \
      float bs_ = (BIAS)[n_];                                                                \
      _Pragma("unroll")                                                                      \
      for (int rt_ = 0; rt_ < 2; ++rt_) {                                                    \
        _Pragma("unroll")                                                                    \
        for (int r_ = 0; r_ < 4; ++r_) {                                                     \
          int row_ = rt_ * 16 + quad * 4 + r_;                                               \
          (Zh)[row_ * 264 + n_] = (short)f2h(sp_f(acc_[rt_][j_][r_] + bs_));                 \
        }                                                                                    \
      }                                                                                      \
    }                                                                                        \
  } while (0)

__global__ __launch_bounds__(256, 1) void rde_fused15(
    const float* __restrict__ x0, const float* __restrict__ logsigs,
    const float* __restrict__ iW1, const float* __restrict__ ib1,
    const float* __restrict__ iW2, const float* __restrict__ ib2,
    const float* __restrict__ iW3, const float* __restrict__ ib3,
    const float* __restrict__ vW1, const float* __restrict__ vb1,
    const float* __restrict__ vW2, const float* __restrict__ vb2,
    const float* __restrict__ vW3, const float* __restrict__ vb3,
    const float* __restrict__ roW, const float* __restrict__ rob,
    float* __restrict__ out,
    unsigned short* hA, unsigned short* hB, unsigned short* hC,
    unsigned short* w1t, unsigned short* w2t, unsigned short* w3t, int* slots) {
    __shared__ Scr S;
    __shared__ float hloc[256];   // owned h sub-tile [32 rows x 8 s], exact f32
    __shared__ float rtmp[44];    // readout partials (4 waves x 10)
    const int tid = threadIdx.x, blk = blockIdx.x;
    const int lane = tid & 63, wv = tid >> 6, quad = lane >> 4, l15 = lane & 15;
    // chunk = blk&7 (== XCD): all 32 blocks of a chunk share one XCD -> sc0 exchange.
    // slot = blk>>3 in 0..31: owns 8 s-cols + 288 W3 rows (register-resident, R15).
    const int chunk = blk & 7;
    const int slot = blk >> 3;
    const int b0c32 = chunk * 32;        // 32 batch rows owned by this chunk
    const int s0g = slot * 8;            // owned s-slice
    const int n0g = slot * 288;          // owned W3 n-slice
    const int nnt = (wv < 2) ? 5 : 4;    // 18 W3 n-tiles over 4 waves
    int* flags = slots + 1024 + chunk * 32;
    const f32x4 zero4 = {0.f, 0.f, 0.f, 0.f};

    // ===== phase 0: init MLP (blk<8), W1/W2 fp16 cast (8..15), W3 fp16 cast (16..255) =====
    if (blk < 8) {
        IScr& I = S.in;
        const int b0 = blk * 32;
        I.x0s[tid >> 3][tid & 7] = x0[(b0 + (tid >> 3)) * DIN + (tid & 7)];
        __syncthreads();
        const int j = tid;
        {
            float w[DIN];
#pragma unroll
            for (int k = 0; k < DIN; ++k) w[k] = iW1[j * DIN + k];
            float bias = ib1[j];
            for (int r = 0; r < 32; ++r) {
                float acc = bias;
#pragma unroll
                for (int k = 0; k < DIN; ++k) acc += I.x0s[r][k] * w[k];
                I.h1[r * 257 + j] = sp_f(acc);
            }
        }
        __syncthreads();
        {
            float bias = ib2[j];
            for (int rb = 0; rb < 4; ++rb) {
                float a8[8];
#pragma unroll
                for (int rr = 0; rr < 8; ++rr) a8[rr] = bias;
                for (int k = 0; k < 256; ++k) {
                    float wvv = iW2[j * 256 + k];
#pragma unroll
                    for (int rr = 0; rr < 8; ++rr) a8[rr] += I.h1[(rb * 8 + rr) * 257 + k] * wvv;
                }
#pragma unroll
                for (int rr = 0; rr < 8; ++rr) I.h2[(rb * 8 + rr) * 257 + j] = sp_f(a8[rr]);
            }
        }
        __syncthreads();
        {
            float bias = ib3[j];
            for (int rb = 0; rb < 4; ++rb) {
                float a8[8];
#pragma unroll
                for (int rr = 0; rr < 8; ++rr) a8[rr] = bias;
                for (int k = 0; k < 256; ++k) {
                    float wvv = iW3[j * 256 + k];
#pragma unroll
                    for (int rr = 0; rr < 8; ++rr) a8[rr] += I.h2[(rb * 8 + rr) * 257 + k] * wvv;
                }
#pragma unroll
                for (int rr = 0; rr < 8; ++rr)   // publish h0 as fp16 into buffer 0 (sc1)
                    sth(&hA[(b0 + rb * 8 + rr) * 256 + j], f2h(a8[rr]));
            }
        }
    } else if (blk < 16) {
        const int idx = blk - 8;
        const float* src = (idx < 4) ? vW1 : vW2;
        unsigned short* dh = (idx < 4) ? w1t : w2t;
        const int part = idx & 3;
        for (int u = part * 2048 + tid; u < (part + 1) * 2048; u += 256)
            cast_w8n_h(src, dh, u, 256);
    } else {
        for (long u = (long)(blk - 16) * 256 + tid; u < 9216L * 32; u += 240L * 256)
            cast_w8n_h(vW3, w3t, u, 9216);
    }
    gbar(slots, 1);

    // ===== R15: ALL weights register-resident (t-invariant) =====
    half8 w1f[4][8], w2f[4][8];
#pragma unroll
    for (int j = 0; j < 4; ++j) {
        int n_ = (4 * wv + j) * 16 + l15;
#pragma unroll
        for (int kt = 0; kt < 8; ++kt) {
            long bo = ((long)kt * 256 + n_) * 32 + quad * 8;
            w1f[j][kt] = *(const half8*)(const void*)(w1t + bo);
            w2f[j][kt] = *(const half8*)(const void*)(w2t + bo);
        }
    }
    // W3: wave's entire slice share = nnt x 8 fragments = <=160 VGPRs, loaded ONCE.
    half8 w3f[5][8];
    {
        const long w3base = ((long)n0g + wv * 16 + l15) * 32 + quad * 8;
#pragma unroll
        for (int i = 0; i < 5; ++i)
            if (i < nnt) {
#pragma unroll
                for (int kk = 0; kk < 8; ++kk)
                    w3f[i][kk] = *(const half8*)(const void*)
                        (w3t + w3base + (long)kk * 294912 + (long)i * 2048);
            }
    }

    // init owned h sub-tile [32 x 8] (sc1 read of h0; exact f32 accumulator)
    if (tid < 64) {
        int r = tid >> 1, part = tid & 1;
        U64F2 a;
        a.u = ldg64(hA + (b0c32 + r) * 256 + s0g + part * 4);
#pragma unroll
        for (int q = 0; q < 4; ++q) hloc[r * 8 + part * 4 + q] = h2f(a.s[q]);
    }
    // prefetch logsigs slice for t=0 into parity-0 buffer
    for (int i = tid; i < 32 * Ll; i += 256) {
        int r = i / Ll, l = i - r * Ll;
        S.g.lss[i] = logsigs[((long)(b0c32 + r) * Tt) * Ll + l];
    }
    __syncthreads();

    // 3-buffer rotation (flags>=t gating bounds drift to <=1 step; chunks independent)
    const unsigned short* h_r = hA;   // read  h(t)
    unsigned short*       h_w = hB;   // write h(t+1)
    unsigned short*       h_s = hC;   // spare

    // ================= main scan: XCD-local sc0 exchange, zero weight traffic =========
    for (int t = 0; t < Tt; ++t) {
        GScr& G = S.g;

        // ---- wait: chunk's 32 slot flags >= t (lanes 0..31 poll in parallel, sc0/L2) ----
        for (;;) {
            int v = t;
            if (lane < 32) {
                const int* fp = flags + lane;
                asm volatile("global_load_dword %0, %1, off sc0\n\ts_waitcnt vmcnt(0)"
                             : "=v"(v) : "v"(fp) : "memory");
            }
            if (__all(v >= t)) break;
            __builtin_amdgcn_s_sleep(1);
        }

        // ---- gather h(t) [32 rows x 256] fp16 via sc0 (8 loads, one waitcnt) ----
        {
            const int r0 = tid >> 6, c4 = (tid & 63) * 4;
            const unsigned short* gp = h_r + (b0c32 + r0) * 256 + c4;
            unsigned long long v0, v1, v2, v3, v4, v5, v6, v7;
            asm volatile(
                "global_load_dwordx2 %0, %8, off sc0\n\t"
                "global_load_dwordx2 %1, %9, off sc0\n\t"
                "global_load_dwordx2 %2, %10, off sc0\n\t"
                "global_load_dwordx2 %3, %11, off sc0\n\t"
                "global_load_dwordx2 %4, %12, off sc0\n\t"
                "global_load_dwordx2 %5, %13, off sc0\n\t"
                "global_load_dwordx2 %6, %14, off sc0\n\t"
                "global_load_dwordx2 %7, %15, off sc0\n\t"
                "s_waitcnt vmcnt(0)"
                : "=&v"(v0), "=&v"(v1), "=&v"(v2), "=&v"(v3),
                  "=&v"(v4), "=&v"(v5), "=&v"(v6), "=&v"(v7)
                : "v"(gp), "v"(gp + 1024), "v"(gp + 2048), "v"(gp + 3072),
                  "v"(gp + 4096), "v"(gp + 5120), "v"(gp + 6144), "v"(gp + 7168)
                : "memory");
            *(unsigned long long*)(void*)&G.hh[(r0     ) * 264 + c4] = v0;
            *(unsigned long long*)(void*)&G.hh[(r0 +  4) * 264 + c4] = v1;
            *(unsigned long long*)(void*)&G.hh[(r0 +  8) * 264 + c4] = v2;
            *(unsigned long long*)(void*)&G.hh[(r0 + 12) * 264 + c4] = v3;
            *(unsigned long long*)(void*)&G.hh[(r0 + 16) * 264 + c4] = v4;
            *(unsigned long long*)(void*)&G.hh[(r0 + 20) * 264 + c4] = v5;
            *(unsigned long long*)(void*)&G.hh[(r0 + 24) * 264 + c4] = v6;
            *(unsigned long long*)(void*)&G.hh[(r0 + 28) * 264 + c4] = v7;
        }
        __syncthreads();

        // ---- stage 1: z1 = sp(h W1^T) ----
        MLP_STAGE32R(G.hh, w1f, vb1, G.z1);
        __syncthreads();

        // ---- stage 2: z2 = sp(z1 W2^T) ----
        MLP_STAGE32R(G.z1, w2f, vb2, G.z2);
        __syncthreads();

        // ---- W3 GEMM (2 row-tiles), B fully register-resident ----
        {
            f32x4 acc[2][5];
#pragma unroll
            for (int rt = 0; rt < 2; ++rt)
#pragma unroll
                for (int i = 0; i < 5; ++i) acc[rt][i] = zero4;
#pragma unroll
            for (int kk = 0; kk < 8; ++kk) {
                half8 ah0 = *(const half8*)(const void*)&G.z2[l15 * 264 + kk * 32 + quad * 8];
                half8 ah1 = *(const half8*)(const void*)&G.z2[(16 + l15) * 264 + kk * 32 + quad * 8];
#pragma unroll
                for (int i = 0; i < 5; ++i)
                    if (i < nnt) {
                        acc[0][i] = __builtin_amdgcn_mfma_f32_16x16x32_f16(ah0, w3f[i][kk], acc[0][i], 0, 0, 0);
                        acc[1][i] = __builtin_amdgcn_mfma_f32_16x16x32_f16(ah1, w3f[i][kk], acc[1][i], 0, 0, 0);
                    }
            }
            // tanh epilogue -> ml
#pragma unroll
            for (int i = 0; i < 5; ++i)
                if (i < nnt) {
                    int nloc = (wv + 4 * i) * 16 + l15;
                    float bias = vb3[n0g + nloc];
#pragma unroll
                    for (int rt = 0; rt < 2; ++rt)
#pragma unroll
                        for (int r = 0; r < 4; ++r) {
                            int row = rt * 16 + quad * 4 + r;
                            G.ml[row * 296 + nloc] = tanh_f(acc[rt][i][r] + bias);
                        }
                }
        }
        __syncthreads();

        // ---- l-contraction: thread (row, sq) owns h[row][s0g+sq]: hloc += dot36 ----
        {
            int row = tid >> 3, sq = tid & 7;
            const f32x4* mp = (const f32x4*)(const void*)&G.ml[row * 296 + sq * 36];
            const f32x4* lp = (const f32x4*)(const void*)&G.lss[(t & 1) * 1152 + row * 36];
            float a = 0.f;
#pragma unroll
            for (int q = 0; q < 9; ++q) {
                f32x4 m4 = mp[q], l4 = lp[q];
                a += m4[0] * l4[0] + m4[1] * l4[1] + m4[2] * l4[2] + m4[3] * l4[3];
            }
            hloc[tid] += a;
        }
        __syncthreads();   // hloc complete

        // ---- publish owned [32 x 8] fp16 via sc0 (wave 0), fence, sc0 flag store ----
        if (tid < 64) {
            int r = tid >> 1, part = tid & 1;
            U64F2 H;
#pragma unroll
            for (int q = 0; q < 4; ++q) H.s[q] = f2h(hloc[r * 8 + part * 4 + q]);
            unsigned short* pp = h_w + (b0c32 + r) * 256 + s0g + part * 4;
            asm volatile("global_store_dwordx2 %0, %1, off sc0" :: "v"(pp), "v"(H.u) : "memory");
            asm volatile("s_waitcnt vmcnt(0)" ::: "memory");
            if (tid == 0) {
                int* fp = flags + slot;
                int fv = t + 1;
                asm volatile("global_store_dword %0, %1, off sc0" :: "v"(fp), "v"(fv) : "memory");
            }
        }

        // ==== wait-window work (off the critical chain) ====
        if (lane < OUTd) {
            const int o = lane;
            float acc = 0.f;
            const short* ph = &G.hh[slot * 264 + wv * 64];
            const float* wp = roW + o * 256 + wv * 64;
            for (int s = 0; s < 64; s += 8) {
                half8 vh = *(const half8*)(const void*)(ph + s);
                f32x4 w0 = *(const f32x4*)(wp + s);
                f32x4 w1 = *(const f32x4*)(wp + s + 4);
#pragma unroll
                for (int q = 0; q < 4; ++q) {
                    acc += (float)vh[q] * w0[q];
                    acc += (float)vh[q + 4] * w1[q];
                }
            }
            rtmp[wv * 10 + o] = acc;
        }
        if (t + 1 < Tt) {
            for (int i = tid; i < 32 * Ll; i += 256) {
                int r = i / Ll, l = i - r * Ll;
                G.lss[((t + 1) & 1) * 1152 + i] =
                    logsigs[((long)(b0c32 + r) * Tt + (t + 1)) * Ll + l];
            }
        }
        __syncthreads();   // rtmp complete
        if (tid < OUTd)
            out[((long)(b0c32 + slot) * 513 + t) * OUTd + tid] =
                rob[tid] + rtmp[tid] + rtmp[10 + tid] + rtmp[20 + tid] + rtmp[30 + tid];

        // rotate buffers
        {
            const unsigned short* t0 = h_r;
            h_r = h_w; h_w = h_s; h_s = (unsigned short*)t0;
        }
    }

    // ---- final readout out[:, 512, :] from h(512) = h_r ----
    {
        for (;;) {
            int v = Tt;
            if (lane < 32) {
                const int* fp = flags + lane;
                asm volatile("global_load_dword %0, %1, off sc0\n\ts_waitcnt vmcnt(0)"
                             : "=v"(v) : "v"(fp) : "memory");
            }
            if (__all(v >= Tt)) break;
            __builtin_amdgcn_s_sleep(1);
        }
        __syncthreads();
        float* fb = S.g.ml;   // reuse as f32 row buffer
        if (tid < 64) {
            int c4 = tid * 4;
            const unsigned short* pp = h_r + (long)(b0c32 + slot) * 256 + c4;
            unsigned long long a;
            asm volatile("global_load_dwordx2 %0, %1, off sc0\n\ts_waitcnt vmcnt(0)"
                         : "=v"(a) : "v"(pp) : "memory");
            U64F2 u; u.u = a;
#pragma unroll
            for (int q = 0; q < 4; ++q) fb[c4 + q] = h2f(u.s[q]);
        }
        __syncthreads();
        if (tid < OUTd) {
            float acc = rob[tid];
            const float* wp = roW + tid * 256;
            for (int s = 0; s < 256; s += 4) {
                f32x4 hv = *(const f32x4*)(fb + s);
                f32x4 w4 = *(const f32x4*)(wp + s);
                acc += hv[0] * w4[0] + hv[1] * w4[1] + hv[2] * w4[2] + hv[3] * w4[3];
            }
            out[((long)(b0c32 + slot) * 513 + Tt) * OUTd + tid] = acc;
        }
    }
}

extern "C" void kernel_launch(void* const* d_in, const int* in_sizes, int n_in,
                              void* d_out, int out_size, void* d_ws, size_t ws_size,
                              hipStream_t stream) {
    const float* x0      = (const float*)d_in[0];
    const float* logsigs = (const float*)d_in[1];
    const float* iW1 = (const float*)d_in[2];
    const float* ib1 = (const float*)d_in[3];
    const float* iW2 = (const float*)d_in[4];
    const float* ib2 = (const float*)d_in[5];
    const float* iW3 = (const float*)d_in[6];
    const float* ib3 = (const float*)d_in[7];
    const float* vW1 = (const float*)d_in[8];
    const float* vb1 = (const float*)d_in[9];
    const float* vW2 = (const float*)d_in[10];
    const float* vb2 = (const float*)d_in[11];
    const float* vW3 = (const float*)d_in[12];
    const float* vb3 = (const float*)d_in[13];
    const float* roW = (const float*)d_in[14];
    const float* rob = (const float*)d_in[15];
    float* out = (float*)d_out;

    char* p = (char*)d_ws;
    unsigned short* hA   = (unsigned short*)p;                // 131072 B (fp16, buf 0)
    unsigned short* hB   = (unsigned short*)(p + 131072);     // 131072 B (buf 1)
    unsigned short* hC   = (unsigned short*)(p + 262144);     // 131072 B (buf 2)
    unsigned short* w1t  = (unsigned short*)(p + 393216);     // 131072 B (fp16)
    unsigned short* w2t  = (unsigned short*)(p + 524288);     // 131072 B (fp16)
    unsigned short* w3t  = (unsigned short*)(p + 655360);     // 4718592 B (fp16)
    int* slots           = (int*)(p + 10485760);              // gbar [0,512], flags [1024,1280)

    hipMemsetAsync(slots, 0, 8192, stream);
    rde_fused15<<<dim3(256), dim3(256), 0, stream>>>(
        x0, logsigs, iW1, ib1, iW2, ib2, iW3, ib3,
        vW1, vb1, vW2, vb2, vW3, vb3, roW, rob, out,
        hA, hB, hC, w1t, w2t, w3t, slots);
}